// Round 12
// baseline (537.645 us; speedup 1.0000x reference)
//
#include <hip/hip_runtime.h>
#include <hip/hip_cooperative_groups.h>
#include <cstddef>

#define CC 128  // channels

namespace cg = cooperative_groups;

typedef __attribute__((ext_vector_type(8))) short bf16x8;
typedef __attribute__((ext_vector_type(4))) float f32x4;

// fp32 -> bf16 (round-to-nearest-even on the bit pattern)
__device__ __forceinline__ unsigned short f2bf(float f)
{
    unsigned int u = __float_as_uint(f);
    u = (u + 0x7fffu + ((u >> 16) & 1u)) >> 16;
    return (unsigned short)u;
}

__device__ __forceinline__ unsigned int pack2(float a, float b)
{
    return (unsigned int)f2bf(a) | ((unsigned int)f2bf(b) << 16);
}

// ===========================================================================
// Shared device bodies (verified R8-R11 code, re-indexed for grid-stride)
// ===========================================================================

// ---- gemm: Bs = 32KB pre-swizzled Wt (staged once), As = 16KB A-tile ------
__device__ __forceinline__ void gemm_stage_B(
    const unsigned short* __restrict__ Wt, unsigned short* Bs, int t)
{
    const uint4* src = (const uint4*)Wt;
    uint4* dst = (uint4*)Bs;
    #pragma unroll
    for (int i = 0; i < 8; ++i) dst[t + 256 * i] = src[t + 256 * i];
}

__device__ __forceinline__ void gemm_tile(
    const float* __restrict__ Xr, const float* __restrict__ Xi,
    unsigned short* __restrict__ Y, int N, int bid,
    const unsigned short* Bs, unsigned short* As, int t)
{
    const int m0 = bid * 64;
    const int M = 2 * N;

    #pragma unroll
    for (int i = 0; i < 4; ++i) {
        const int blk = t + 256 * i;
        const int r  = blk >> 4;          // 0..63
        const int k0 = (blk & 15) * 8;    // 0..120
        const int m  = m0 + r;
        float4 q0 = make_float4(0.f, 0.f, 0.f, 0.f);
        float4 q1 = make_float4(0.f, 0.f, 0.f, 0.f);
        if (m < M) {
            const float* src = (m < N) ? (Xr + (size_t)m * CC)
                                       : (Xi + (size_t)(m - N) * CC);
            q0 = *(const float4*)(src + k0);
            q1 = *(const float4*)(src + k0 + 4);
        }
        uint4 h;
        h.x = pack2(q0.x, q0.y);
        h.y = pack2(q0.z, q0.w);
        h.z = pack2(q1.x, q1.y);
        h.w = pack2(q1.z, q1.w);
        const int byte = r * 256 + ((2 * k0) ^ ((r & 7) << 4));
        *(uint4*)((char*)As + byte) = h;
    }
    __syncthreads();

    const int w = t >> 6, lane = t & 63;
    const int wr = w >> 1, wc = w & 1;     // 2x2 wave grid
    const int r0 = wr * 32;
    const int c0 = wc * 64;
    const int lr = lane & 15;
    const int lk = lane >> 4;

    f32x4 acc[2][4];
    #pragma unroll
    for (int a = 0; a < 2; ++a)
        #pragma unroll
        for (int b = 0; b < 4; ++b)
            acc[a][b] = (f32x4){0.f, 0.f, 0.f, 0.f};

    #pragma unroll
    for (int kk = 0; kk < 4; ++kk) {
        const int kbase = kk * 32 + lk * 8;
        bf16x8 afrag[2];
        #pragma unroll
        for (int at = 0; at < 2; ++at) {
            const int row = r0 + at * 16 + lr;
            afrag[at] = *(const bf16x8*)((const char*)As +
                row * 256 + ((2 * kbase) ^ ((row & 7) << 4)));
        }
        #pragma unroll
        for (int bt = 0; bt < 4; ++bt) {
            const int col = c0 + bt * 16 + lr;
            const bf16x8 bfrag = *(const bf16x8*)((const char*)Bs +
                col * 256 + ((2 * kbase) ^ ((col & 7) << 4)));
            acc[0][bt] = __builtin_amdgcn_mfma_f32_16x16x32_bf16(
                afrag[0], bfrag, acc[0][bt], 0, 0, 0);
            acc[1][bt] = __builtin_amdgcn_mfma_f32_16x16x32_bf16(
                afrag[1], bfrag, acc[1][bt], 0, 0, 0);
        }
    }

    #pragma unroll
    for (int at = 0; at < 2; ++at) {
        #pragma unroll
        for (int v = 0; v < 4; ++v) {
            const int m = m0 + r0 + at * 16 + lk * 4 + v;
            if (m >= M) continue;
            const int node = (m < N) ? m : m - N;
            const int half = (m < N) ? 0 : 128;
            unsigned short* dst = Y + (size_t)node * 256 + half;
            #pragma unroll
            for (int bt = 0; bt < 4; ++bt)
                dst[c0 + bt * 16 + lr] = f2bf(acc[at][bt][v]);
        }
    }
}

// ---- fill quad (atomic-free): pos = rbase[e&3][row] + rank[e] -------------
__device__ __forceinline__ void fill_quad(
    const int* __restrict__ row, const int* __restrict__ col,
    const float* __restrict__ Lr, const float* __restrict__ Li,
    const int* __restrict__ rbase, const int* __restrict__ rank,
    int4* __restrict__ meta, int N, int E, int base)
{
    if (base + 3 < E) {               // base%4==0 -> reps are exactly 0,1,2,3
        const int4   r4 = *(const int4*)(row + base);
        const int4   c4 = *(const int4*)(col + base);
        const float4 a4 = *(const float4*)(Lr + base);
        const float4 b4 = *(const float4*)(Li + base);
        const int4   k4 = *(const int4*)(rank + base);
        meta[rbase[r4.x] + k4.x] =
            make_int4(c4.x, __float_as_int(a4.x), __float_as_int(b4.x), 0);
        meta[rbase[N + r4.y] + k4.y] =
            make_int4(c4.y, __float_as_int(a4.y), __float_as_int(b4.y), 0);
        meta[rbase[2 * N + r4.z] + k4.z] =
            make_int4(c4.z, __float_as_int(a4.z), __float_as_int(b4.z), 0);
        meta[rbase[3 * N + r4.w] + k4.w] =
            make_int4(c4.w, __float_as_int(a4.w), __float_as_int(b4.w), 0);
    } else {
        for (int e = base; e < E; ++e)
            meta[rbase[(size_t)(e & 3) * N + row[e]] + rank[e]] =
                make_int4(col[e], __float_as_int(Lr[e]), __float_as_int(Li[e]), 0);
    }
}

// ---- hist quad: 4-bank counts + rank = atomicAdd return -------------------
__device__ __forceinline__ void hist_quad(
    const int* __restrict__ row, int* __restrict__ counts,
    int* __restrict__ rank, int N, int E, int base)
{
    if (base + 3 < E) {
        const int4 r4 = *(const int4*)(row + base);
        int4 k4;
        k4.x = atomicAdd(counts + 0 * N + r4.x, 1);
        k4.y = atomicAdd(counts + 1 * N + r4.y, 1);
        k4.z = atomicAdd(counts + 2 * N + r4.z, 1);
        k4.w = atomicAdd(counts + 3 * N + r4.w, 1);
        *(int4*)(rank + base) = k4;
    } else {
        for (int e = base; e < E; ++e)
            rank[e] = atomicAdd(counts + (size_t)(e & 3) * N + row[e], 1);
    }
}

// ---- gather (verified 74us body), one node n, 2 ch/lane, 8-edge chunks ----
__device__ __forceinline__ void cmadd_bf(
    const int4 m, const unsigned int ur, const unsigned int ui,
    float2& aR, float2& aI)
{
    const float lr = __int_as_float(m.y);
    const float li = __int_as_float(m.z);
    const float yrx = __uint_as_float(ur << 16);
    const float yry = __uint_as_float(ur & 0xFFFF0000u);
    const float yix = __uint_as_float(ui << 16);
    const float yiy = __uint_as_float(ui & 0xFFFF0000u);
    aR.x += lr * yrx - li * yix;
    aR.y += lr * yry - li * yiy;
    aI.x += li * yrx + lr * yix;
    aI.y += li * yry + lr * yiy;
}

__device__ __forceinline__ void edge_acc(
    const int4 m, const unsigned short* __restrict__ Y,
    int lane, float2& aR, float2& aI)
{
    const unsigned short* b = Y + (size_t)m.x * 256 + 2 * lane;
    const unsigned int ur = *(const unsigned int*)(b);
    const unsigned int ui = *(const unsigned int*)(b + 128);
    cmadd_bf(m, ur, ui, aR, aI);
}

__device__ __forceinline__ void gather_node(
    const unsigned short* __restrict__ Y,
    const float* __restrict__ Xr, const float* __restrict__ Xi,
    const int* __restrict__ offsets, const int4* __restrict__ meta,
    float* __restrict__ out, int N, int E, int n, int lane)
{
    const int start = offsets[n];
    const int end   = (n + 1 < N) ? offsets[n + 1] : E;
    const int Em1 = E - 1;

    float2 aR = *(const float2*)(Xr + (size_t)n * CC + 2 * lane);
    float2 aI = *(const float2*)(Xi + (size_t)n * CC + 2 * lane);

    int4 m0 = meta[min(start + 0, Em1)];
    int4 m1 = meta[min(start + 1, Em1)];
    int4 m2 = meta[min(start + 2, Em1)];
    int4 m3 = meta[min(start + 3, Em1)];
    int4 m4 = meta[min(start + 4, Em1)];
    int4 m5 = meta[min(start + 5, Em1)];
    int4 m6 = meta[min(start + 6, Em1)];
    int4 m7 = meta[min(start + 7, Em1)];

    int j = start;
    for (; j + 8 <= end; j += 8) {
        const int4 n0 = meta[min(j +  8, Em1)];
        const int4 n1 = meta[min(j +  9, Em1)];
        const int4 n2 = meta[min(j + 10, Em1)];
        const int4 n3 = meta[min(j + 11, Em1)];
        const int4 n4 = meta[min(j + 12, Em1)];
        const int4 n5 = meta[min(j + 13, Em1)];
        const int4 n6 = meta[min(j + 14, Em1)];
        const int4 n7 = meta[min(j + 15, Em1)];
        const unsigned short* b0 = Y + (size_t)m0.x * 256 + 2 * lane;
        const unsigned short* b1 = Y + (size_t)m1.x * 256 + 2 * lane;
        const unsigned short* b2 = Y + (size_t)m2.x * 256 + 2 * lane;
        const unsigned short* b3 = Y + (size_t)m3.x * 256 + 2 * lane;
        const unsigned short* b4 = Y + (size_t)m4.x * 256 + 2 * lane;
        const unsigned short* b5 = Y + (size_t)m5.x * 256 + 2 * lane;
        const unsigned short* b6 = Y + (size_t)m6.x * 256 + 2 * lane;
        const unsigned short* b7 = Y + (size_t)m7.x * 256 + 2 * lane;
        const unsigned int ur0 = *(const unsigned int*)(b0);
        const unsigned int ui0 = *(const unsigned int*)(b0 + 128);
        const unsigned int ur1 = *(const unsigned int*)(b1);
        const unsigned int ui1 = *(const unsigned int*)(b1 + 128);
        const unsigned int ur2 = *(const unsigned int*)(b2);
        const unsigned int ui2 = *(const unsigned int*)(b2 + 128);
        const unsigned int ur3 = *(const unsigned int*)(b3);
        const unsigned int ui3 = *(const unsigned int*)(b3 + 128);
        const unsigned int ur4 = *(const unsigned int*)(b4);
        const unsigned int ui4 = *(const unsigned int*)(b4 + 128);
        const unsigned int ur5 = *(const unsigned int*)(b5);
        const unsigned int ui5 = *(const unsigned int*)(b5 + 128);
        const unsigned int ur6 = *(const unsigned int*)(b6);
        const unsigned int ui6 = *(const unsigned int*)(b6 + 128);
        const unsigned int ur7 = *(const unsigned int*)(b7);
        const unsigned int ui7 = *(const unsigned int*)(b7 + 128);

        cmadd_bf(m0, ur0, ui0, aR, aI);
        cmadd_bf(m1, ur1, ui1, aR, aI);
        cmadd_bf(m2, ur2, ui2, aR, aI);
        cmadd_bf(m3, ur3, ui3, aR, aI);
        cmadd_bf(m4, ur4, ui4, aR, aI);
        cmadd_bf(m5, ur5, ui5, aR, aI);
        cmadd_bf(m6, ur6, ui6, aR, aI);
        cmadd_bf(m7, ur7, ui7, aR, aI);

        m0 = n0; m1 = n1; m2 = n2; m3 = n3;
        m4 = n4; m5 = n5; m6 = n6; m7 = n7;
    }
    const int r = end - j;
    if (r > 0) edge_acc(m0, Y, lane, aR, aI);
    if (r > 1) edge_acc(m1, Y, lane, aR, aI);
    if (r > 2) edge_acc(m2, Y, lane, aR, aI);
    if (r > 3) edge_acc(m3, Y, lane, aR, aI);
    if (r > 4) edge_acc(m4, Y, lane, aR, aI);
    if (r > 5) edge_acc(m5, Y, lane, aR, aI);
    if (r > 6) edge_acc(m6, Y, lane, aR, aI);

    *(float2*)(out + (size_t)n * CC + 2 * lane) = aR;
    *(float2*)(out + ((size_t)n + N) * CC + 2 * lane) = aI;
}

// ===========================================================================
// MEGA: whole pipeline in ONE cooperative dispatch. 7 launches -> 1; the
// ~10us drain+launch cost per boundary (6 boundaries) becomes ~2us grid syncs.
// Phases: P0 zero+convW | P1 gemm+hist | P2-P4 scans | P5 fill | P6 gather.
// Grid size is occupancy-query-driven (co-residency guaranteed); all phases
// are grid-stride, so any G >= 1 is correct.
// ===========================================================================
__global__ __launch_bounds__(256) void mega(
    const int* __restrict__ row, const int* __restrict__ col,
    const float* __restrict__ Lr, const float* __restrict__ Li,
    const float* __restrict__ W,
    const float* __restrict__ Xr, const float* __restrict__ Xi,
    int* __restrict__ counts, int* __restrict__ rank,
    int* __restrict__ rbase, int* __restrict__ bsum, int* __restrict__ bpre,
    int4* __restrict__ meta, unsigned short* __restrict__ Wt,
    unsigned short* __restrict__ Y, float* __restrict__ out,
    int N, int E, int NB, int G_gemm)
{
    cg::grid_group gg = cg::this_grid();
    __shared__ char smem[49152];            // 48KB: gemm Bs(32K)+As(16K); scans alias
    unsigned short* Bs = (unsigned short*)smem;
    unsigned short* As = (unsigned short*)(smem + 32768);
    int* si = (int*)smem;

    const int t  = threadIdx.x;
    const int gb = blockIdx.x;
    const int G  = gridDim.x;
    const int NQ = (E + 3) >> 2;            // edge quads

    // ---- P0: zero counts + convert/swizzle W -----------------------------
    for (int i = gb * 256 + t; i < 4 * N; i += G * 256) counts[i] = 0;
    for (int idx = gb * 256 + t; idx < CC * CC; idx += G * 256) {
        const int k = idx >> 7;
        const int n = idx & 127;
        const unsigned int sw =
            ((unsigned)(2 * k) ^ (((unsigned)n & 7u) << 4)) >> 1;
        Wt[(size_t)n * 128 + sw] = f2bf(W[idx]);
    }
    gg.sync();

    // ---- P1: gemm tiles (grid-stride) + histogram ------------------------
    gemm_stage_B(Wt, Bs, t);
    for (int bid = gb; bid < G_gemm; bid += G) {
        __syncthreads();                    // prior tile's LDS readers done
        gemm_tile(Xr, Xi, Y, N, bid, Bs, As, t);
    }
    for (int qi = gb * 256 + t; qi < NQ; qi += G * 256)
        hist_quad(row, counts, rank, N, E, qi * 4);
    gg.sync();

    // ---- P2: per-256-chunk row-total reduce -> bsum ----------------------
    for (int b = gb; b < NB; b += G) {
        const int idx = b * 256 + t;
        int v = 0;
        if (idx < N)
            v = counts[idx] + counts[N + idx] + counts[2 * N + idx]
              + counts[3 * N + idx];
        si[t] = v;
        __syncthreads();
        #pragma unroll
        for (int off = 128; off > 0; off >>= 1) {
            if (t < off) si[t] += si[t + off];
            __syncthreads();
        }
        if (t == 0) bsum[b] = si[0];
        __syncthreads();
    }
    gg.sync();

    // ---- P3: exclusive scan of block sums (block 0) ----------------------
    if (gb == 0) {
        si[t] = (t < NB) ? bsum[t] : 0;
        __syncthreads();
        #pragma unroll
        for (int off = 1; off < 256; off <<= 1) {
            const int v = si[t];
            const int u = (t >= off) ? si[t - off] : 0;
            __syncthreads();
            si[t] = v + u;
            __syncthreads();
        }
        if (t < NB) bpre[t] = t ? si[t - 1] : 0;
    }
    gg.sync();

    // ---- P4: final scan -> replica bases ---------------------------------
    for (int b = gb; b < NB; b += G) {
        const int idx = b * 256 + t;
        int c0 = 0, c1 = 0, c2 = 0, c3 = 0;
        if (idx < N) {
            c0 = counts[idx];
            c1 = counts[N + idx];
            c2 = counts[2 * N + idx];
            c3 = counts[3 * N + idx];
        }
        const int v = c0 + c1 + c2 + c3;
        si[t] = v;
        __syncthreads();
        #pragma unroll
        for (int off = 1; off < 256; off <<= 1) {
            const int a = si[t];
            const int u = (t >= off) ? si[t - off] : 0;
            __syncthreads();
            si[t] = a + u;
            __syncthreads();
        }
        if (idx < N) {
            const int off = bpre[b] + si[t] - v;  // exclusive row start
            rbase[idx]         = off;
            rbase[N + idx]     = off + c0;
            rbase[2 * N + idx] = off + c0 + c1;
            rbase[3 * N + idx] = off + c0 + c1 + c2;
        }
        __syncthreads();
    }
    gg.sync();

    // ---- P5: atomic-free fill --------------------------------------------
    for (int qi = gb * 256 + t; qi < NQ; qi += G * 256)
        fill_quad(row, col, Lr, Li, rbase, rank, meta, N, E, qi * 4);
    gg.sync();

    // ---- P6: fused gather -------------------------------------------------
    {
        const int lane = t & 63;
        const int wv = t >> 6;
        const int NG = (N + 3) / 4;
        for (int g = gb; g < NG; g += G) {
            const int n = g * 4 + wv;
            if (n < N)
                gather_node(Y, Xr, Xi, rbase /*offsets*/, meta, out, N, E,
                            n, lane);
        }
    }
}

// ===========================================================================
// Fallback path (R11-verified multi-kernel chain)
// ===========================================================================

__global__ __launch_bounds__(256) void hist_conv_fused(
    const int* __restrict__ row, int* __restrict__ counts,
    int* __restrict__ rank, int N, int E,
    const float* __restrict__ W, unsigned short* __restrict__ Wt, int G_conv)
{
    const int bid = blockIdx.x;
    if (bid < G_conv) {
        const int idx = bid * 256 + threadIdx.x;
        if (idx >= CC * CC) return;
        const int k = idx >> 7;
        const int n = idx & 127;
        const unsigned int sw =
            ((unsigned)(2 * k) ^ (((unsigned)n & 7u) << 4)) >> 1;
        Wt[(size_t)n * 128 + sw] = f2bf(W[idx]);
        return;
    }
    hist_quad(row, counts, rank, N, E,
              ((bid - G_conv) * 256 + threadIdx.x) * 4);
}

__global__ __launch_bounds__(256) void scan_block_reduce(
    const int* __restrict__ counts, int* __restrict__ bsum, int N)
{
    __shared__ int s[256];
    const int t = threadIdx.x;
    const int idx = blockIdx.x * 256 + t;
    int v = 0;
    if (idx < N)
        v = counts[idx] + counts[N + idx] + counts[2 * N + idx]
          + counts[3 * N + idx];
    s[t] = v;
    __syncthreads();
    #pragma unroll
    for (int off = 128; off > 0; off >>= 1) {
        if (t < off) s[t] += s[t + off];
        __syncthreads();
    }
    if (t == 0) bsum[blockIdx.x] = s[0];
}

__global__ __launch_bounds__(256) void scan_bsum(
    const int* __restrict__ bsum, int* __restrict__ bpre, int NB)
{
    __shared__ int s[256];
    const int t = threadIdx.x;
    s[t] = (t < NB) ? bsum[t] : 0;
    __syncthreads();
    #pragma unroll
    for (int off = 1; off < 256; off <<= 1) {
        const int v = s[t];
        const int u = (t >= off) ? s[t - off] : 0;
        __syncthreads();
        s[t] = v + u;
        __syncthreads();
    }
    if (t < NB) bpre[t] = t ? s[t - 1] : 0;
}

__global__ __launch_bounds__(256) void scan_final(
    const int* __restrict__ counts, const int* __restrict__ bpre,
    int* __restrict__ rbase, int N)
{
    __shared__ int s[256];
    const int t = threadIdx.x;
    const int idx = blockIdx.x * 256 + t;
    int c0 = 0, c1 = 0, c2 = 0, c3 = 0;
    if (idx < N) {
        c0 = counts[idx];
        c1 = counts[N + idx];
        c2 = counts[2 * N + idx];
        c3 = counts[3 * N + idx];
    }
    const int v = c0 + c1 + c2 + c3;
    s[t] = v;
    __syncthreads();
    #pragma unroll
    for (int off = 1; off < 256; off <<= 1) {
        const int a = s[t];
        const int u = (t >= off) ? s[t - off] : 0;
        __syncthreads();
        s[t] = a + u;
        __syncthreads();
    }
    if (idx < N) {
        const int off = bpre[blockIdx.x] + s[t] - v;
        rbase[idx]         = off;
        rbase[N + idx]     = off + c0;
        rbase[2 * N + idx] = off + c0 + c1;
        rbase[3 * N + idx] = off + c0 + c1 + c2;
    }
}

__global__ __launch_bounds__(256) void fill_gemm_fused(
    const int* __restrict__ row, const int* __restrict__ col,
    const float* __restrict__ Lr, const float* __restrict__ Li,
    const int* __restrict__ rbase, const int* __restrict__ rank,
    int4* __restrict__ meta,
    const float* __restrict__ Xr, const float* __restrict__ Xi,
    const unsigned short* __restrict__ Wt, unsigned short* __restrict__ Y,
    int N, int E, int G_gemm)
{
    __shared__ char smem[49152];
    const int bid = blockIdx.x;
    if (bid < G_gemm) {
        unsigned short* Bs = (unsigned short*)smem;
        unsigned short* As = (unsigned short*)(smem + 32768);
        gemm_stage_B(Wt, Bs, threadIdx.x);
        gemm_tile(Xr, Xi, Y, N, bid, Bs, As, threadIdx.x);
    } else {
        fill_quad(row, col, Lr, Li, rbase, rank, meta, N, E,
                  ((bid - G_gemm) * 256 + threadIdx.x) * 4);
    }
}

__global__ __launch_bounds__(256) void gather_fused(
    const unsigned short* __restrict__ Y,
    const float* __restrict__ Xr, const float* __restrict__ Xi,
    const int* __restrict__ offsets, const int4* __restrict__ meta,
    float* __restrict__ out, int N, int E)
{
    const int n = blockIdx.x * 4 + (threadIdx.x >> 6);
    if (n >= N) return;
    gather_node(Y, Xr, Xi, offsets, meta, out, N, E, n, threadIdx.x & 63);
}

// ---- legacy fp32 fallbacks (small-ws paths) -------------------------------
__global__ __launch_bounds__(256) void gather_nodes(
    const float* __restrict__ Xr, const float* __restrict__ Xi,
    const int* __restrict__ offsets, const int4* __restrict__ meta,
    float* __restrict__ out, int N, int E)
{
    const int n = blockIdx.x * 4 + (threadIdx.x >> 6);
    if (n >= N) return;
    const int lane = threadIdx.x & 63;
    const int start = offsets[n];
    const int end   = (n + 1 < N) ? offsets[n + 1] : E;
    float2 aR = make_float2(0.f, 0.f);
    float2 aI = make_float2(0.f, 0.f);
    for (int j = start; j < end; ++j) {
        const int4 m0 = meta[j];
        const float2 xr0 = *(const float2*)(Xr + (size_t)m0.x * CC + 2 * lane);
        const float2 xi0 = *(const float2*)(Xi + (size_t)m0.x * CC + 2 * lane);
        const float lr0 = __int_as_float(m0.y), li0 = __int_as_float(m0.z);
        aR.x += lr0 * xr0.x - li0 * xi0.x;
        aR.y += lr0 * xr0.y - li0 * xi0.y;
        aI.x += li0 * xr0.x + lr0 * xi0.x;
        aI.y += li0 * xr0.y + lr0 * xi0.y;
    }
    *(float2*)(out + (size_t)n * CC + 2 * lane) = aR;
    *(float2*)(out + ((size_t)n + N) * CC + 2 * lane) = aI;
}

__global__ __launch_bounds__(256) void scatter_edges(
    const float* __restrict__ Xr, const float* __restrict__ Xi,
    const float* __restrict__ Lr, const float* __restrict__ Li,
    const int* __restrict__ row, const int* __restrict__ col,
    float* __restrict__ out, int N, int E)
{
    const int e = blockIdx.x * 4 + (threadIdx.x >> 6);
    if (e >= E) return;
    const int lane = threadIdx.x & 63;
    const int r = row[e], c = col[e];
    const float lr = Lr[e];
    const float li = Li[e];
    const float2 xr = *(const float2*)(Xr + (size_t)c * CC + 2 * lane);
    const float2 xi = *(const float2*)(Xi + (size_t)c * CC + 2 * lane);
    float* pr = out + (size_t)r * CC + 2 * lane;
    float* pi = out + ((size_t)r + N) * CC + 2 * lane;
    unsafeAtomicAdd(pr,     lr * xr.x - li * xi.x);
    unsafeAtomicAdd(pr + 1, lr * xr.y - li * xi.y);
    unsafeAtomicAdd(pi,     li * xr.x + lr * xi.x);
    unsafeAtomicAdd(pi + 1, li * xr.y + lr * xi.y);
}

__global__ __launch_bounds__(256) void hist_rank_fb(
    const int* __restrict__ row, int* __restrict__ counts,
    int* __restrict__ rank, int N, int E)
{
    hist_quad(row, counts, rank, N, E,
              (blockIdx.x * 256 + threadIdx.x) * 4);
}

__global__ __launch_bounds__(256) void fill_csr_fb(
    const int* __restrict__ row, const int* __restrict__ col,
    const float* __restrict__ Lr, const float* __restrict__ Li,
    const int* __restrict__ rbase, const int* __restrict__ rank,
    int4* __restrict__ meta, int N, int E)
{
    fill_quad(row, col, Lr, Li, rbase, rank, meta, N, E,
              (blockIdx.x * 256 + threadIdx.x) * 4);
}

__global__ __launch_bounds__(256) void gemm_inplace(
    float* __restrict__ io, const float* __restrict__ W,
    const float* __restrict__ Xp, int N)
{
    __shared__ float Ws[64 * CC];
    __shared__ float AsT[CC][36];
    const int t = threadIdx.x;
    const int m0 = blockIdx.x * 32;

    for (int ch = t; ch < 1024; ch += 256) {
        const int r  = ch >> 5;
        const int k0 = (ch & 31) * 4;
        const int m  = m0 + r;
        float4 q = make_float4(0.f, 0.f, 0.f, 0.f);
        if (m < N) q = *(const float4*)(io + (size_t)m * CC + k0);
        AsT[k0 + 0][r] = q.x;
        AsT[k0 + 1][r] = q.y;
        AsT[k0 + 2][r] = q.z;
        AsT[k0 + 3][r] = q.w;
    }

    const int cg_ = t & 31;
    const int rs = t >> 5;
    float s[4][4];
    #pragma unroll
    for (int a = 0; a < 4; ++a)
        #pragma unroll
        for (int b = 0; b < 4; ++b) s[a][b] = 0.f;

    for (int kc = 0; kc < 2; ++kc) {
        __syncthreads();
        {
            const float4* src = (const float4*)(W + (size_t)kc * 64 * CC);
            float4* dst = (float4*)Ws;
            #pragma unroll
            for (int i = 0; i < 8; ++i) dst[t + 256 * i] = src[t + 256 * i];
        }
        __syncthreads();
        #pragma unroll 4
        for (int kk = 0; kk < 64; ++kk) {
            const int k = kc * 64 + kk;
            const float4 av = *(const float4*)&AsT[k][rs * 4];
            const float4 wv = *(const float4*)&Ws[kk * CC + cg_ * 4];
            const float ar[4] = {av.x, av.y, av.z, av.w};
            const float wc[4] = {wv.x, wv.y, wv.z, wv.w};
            #pragma unroll
            for (int a = 0; a < 4; ++a)
                #pragma unroll
                for (int b = 0; b < 4; ++b) s[a][b] += ar[a] * wc[b];
        }
    }

    #pragma unroll
    for (int a = 0; a < 4; ++a) {
        const int m = m0 + rs * 4 + a;
        if (m >= N) continue;
        const float4 xv = *(const float4*)(Xp + (size_t)m * CC + cg_ * 4);
        float4 o;
        o.x = s[a][0] + xv.x;
        o.y = s[a][1] + xv.y;
        o.z = s[a][2] + xv.z;
        o.w = s[a][3] + xv.w;
        *(float4*)(io + (size_t)m * CC + cg_ * 4) = o;
    }
}

// ===========================================================================
extern "C" void kernel_launch(void* const* d_in, const int* in_sizes, int n_in,
                              void* d_out, int out_size, void* d_ws, size_t ws_size,
                              hipStream_t stream)
{
    const float* Xr = (const float*)d_in[0];
    const float* Xi = (const float*)d_in[1];
    const float* Lr = (const float*)d_in[2];
    const float* Li = (const float*)d_in[3];
    const float* W  = (const float*)d_in[4];
    const int* row = (const int*)d_in[5];
    const int* col = (const int*)d_in[6];
    float* out = (float*)d_out;

    int N = in_sizes[0] / CC;     // 50000
    int E = in_sizes[2];          // 800000
    int NB = (N + 255) / 256;     // scan blocks (196 <= 256)
    const int EB4 = ((E + 3) / 4 + 255) / 256;
    const int G_conv = (CC * CC + 255) / 256;   // 64
    int G_gemm = (2 * N + 63) / 64;             // 1563

    const size_t y_bytes    = (size_t)N * 256 * sizeof(unsigned short);
    const size_t wt_bytes   = (size_t)CC * CC * sizeof(unsigned short);
    const size_t meta_bytes = (size_t)E * 16;
    const size_t int_bytes  = ((size_t)8 * N + 512 + E) * sizeof(int);
    const size_t need_csr   = meta_bytes + int_bytes;
    const size_t need_fused = y_bytes + wt_bytes + need_csr;

    // One-time occupancy/support query for the cooperative mega-kernel.
    static int mega_grid = -2;   // -2 unqueried; <=0 unsupported
    if (mega_grid == -2) {
        mega_grid = 0;
        int dev = 0, coop = 0, ncu = 0, bpc = 0;
        if (hipGetDevice(&dev) == hipSuccess &&
            hipDeviceGetAttribute(&coop, hipDeviceAttributeCooperativeLaunch,
                                  dev) == hipSuccess && coop &&
            hipDeviceGetAttribute(&ncu,
                                  hipDeviceAttributeMultiprocessorCount,
                                  dev) == hipSuccess && ncu > 0 &&
            hipOccupancyMaxActiveBlocksPerMultiprocessor(
                &bpc, reinterpret_cast<const void*>(mega), 256, 0)
                == hipSuccess && bpc > 0) {
            mega_grid = bpc * ncu;
        }
    }

    if (ws_size >= need_fused) {
        unsigned short* Y  = (unsigned short*)d_ws;
        unsigned short* Wt = (unsigned short*)((char*)d_ws + y_bytes);
        int4*  meta   = (int4*)((char*)d_ws + y_bytes + wt_bytes);
        int*   counts = (int*)((char*)d_ws + y_bytes + wt_bytes + meta_bytes);
        int*   rbase  = counts + 4 * N;
        int*   bsum   = rbase + 4 * N;
        int*   bpre   = bsum + 256;
        int*   rank   = bpre + 256;

        bool launched = false;
        if (mega_grid > 0) {
            void* kargs[] = {
                (void*)&row, (void*)&col, (void*)&Lr, (void*)&Li,
                (void*)&W, (void*)&Xr, (void*)&Xi,
                (void*)&counts, (void*)&rank, (void*)&rbase,
                (void*)&bsum, (void*)&bpre,
                (void*)&meta, (void*)&Wt, (void*)&Y, (void*)&out,
                (void*)&N, (void*)&E, (void*)&NB, (void*)&G_gemm };
            launched = hipLaunchCooperativeKernel(
                reinterpret_cast<const void*>(mega),
                dim3(mega_grid), dim3(256), kargs, 0, stream) == hipSuccess;
            if (!launched) mega_grid = 0;   // don't retry on later calls
        }
        if (!launched) {
            hipMemsetAsync(counts, 0, (size_t)4 * N * sizeof(int), stream);
            hist_conv_fused<<<dim3(G_conv + EB4), dim3(256), 0, stream>>>(
                row, counts, rank, N, E, W, Wt, G_conv);
            scan_block_reduce<<<dim3(NB), dim3(256), 0, stream>>>(counts, bsum, N);
            scan_bsum<<<dim3(1), dim3(256), 0, stream>>>(bsum, bpre, NB);
            scan_final<<<dim3(NB), dim3(256), 0, stream>>>(counts, bpre, rbase, N);
            fill_gemm_fused<<<dim3(G_gemm + EB4), dim3(256), 0, stream>>>(
                row, col, Lr, Li, rbase, rank, meta, Xr, Xi, Wt, Y, N, E, G_gemm);
            gather_fused<<<dim3((N + 3) / 4), dim3(256), 0, stream>>>(
                Y, Xr, Xi, rbase, meta, out, N, E);
        }
    } else if (ws_size >= need_csr) {
        int4* meta    = (int4*)d_ws;
        int*  counts  = (int*)((char*)d_ws + meta_bytes);
        int*  rbase   = counts + 4 * N;
        int*  bsum    = rbase + 4 * N;
        int*  bpre    = bsum + 256;
        int*  rank    = bpre + 256;

        hipMemsetAsync(counts, 0, (size_t)4 * N * sizeof(int), stream);
        hist_rank_fb<<<dim3(EB4), dim3(256), 0, stream>>>(row, counts, rank, N, E);
        scan_block_reduce<<<dim3(NB), dim3(256), 0, stream>>>(counts, bsum, N);
        scan_bsum<<<dim3(1), dim3(256), 0, stream>>>(bsum, bpre, NB);
        scan_final<<<dim3(NB), dim3(256), 0, stream>>>(counts, bpre, rbase, N);
        fill_csr_fb<<<dim3(EB4), dim3(256), 0, stream>>>(
            row, col, Lr, Li, rbase, rank, meta, N, E);
        gather_nodes<<<dim3((N + 3) / 4), dim3(256), 0, stream>>>(
            Xr, Xi, rbase, meta, out, N, E);
        gemm_inplace<<<dim3((N + 31) / 32), dim3(256), 0, stream>>>(out, W, Xr, N);
        gemm_inplace<<<dim3((N + 31) / 32), dim3(256), 0, stream>>>(
            out + (size_t)N * CC, W, Xi, N);
    } else {
        hipMemsetAsync(out, 0, (size_t)2 * N * CC * sizeof(float), stream);
        scatter_edges<<<dim3((E + 3) / 4), dim3(256), 0, stream>>>(
            Xr, Xi, Lr, Li, row, col, out, N, E);
        gemm_inplace<<<dim3((N + 31) / 32), dim3(256), 0, stream>>>(out, W, Xr, N);
        gemm_inplace<<<dim3((N + 31) / 32), dim3(256), 0, stream>>>(
            out + (size_t)N * CC, W, Xi, N);
    }
}

// Round 13
// 283.358 us; speedup vs baseline: 1.8974x; 1.8974x over previous
//
#include <hip/hip_runtime.h>
#include <cstddef>

#define CC 128  // channels

typedef __attribute__((ext_vector_type(8))) short bf16x8;
typedef __attribute__((ext_vector_type(4))) float f32x4;

// fp32 -> bf16 (round-to-nearest-even on the bit pattern)
__device__ __forceinline__ unsigned short f2bf(float f)
{
    unsigned int u = __float_as_uint(f);
    u = (u + 0x7fffu + ((u >> 16) & 1u)) >> 16;
    return (unsigned short)u;
}

__device__ __forceinline__ unsigned int pack2(float a, float b)
{
    return (unsigned int)f2bf(a) | ((unsigned int)f2bf(b) << 16);
}

// ===========================================================================
// CSR build: 4-bank histogram(+rank) -> single-kernel decoupled-lookback scan
// -> atomic-free fill (fused with MFMA gemm). R12 lesson: separate stream
// dispatches are CHEAP (~2us); cooperative grid.sync phases are EXPENSIVE on
// 8 non-coherent XCDs (L2 flush per sync + occupancy coupling) -- mega was
// 2.6x slower. Stay multi-kernel.
// ===========================================================================

// ---- hist quad: 4-bank counts + rank = atomicAdd return -------------------
__device__ __forceinline__ void hist_quad(
    const int* __restrict__ row, int* __restrict__ counts,
    int* __restrict__ rank, int N, int E, int base)
{
    if (base + 3 < E) {
        const int4 r4 = *(const int4*)(row + base);
        int4 k4;
        k4.x = atomicAdd(counts + 0 * N + r4.x, 1);
        k4.y = atomicAdd(counts + 1 * N + r4.y, 1);
        k4.z = atomicAdd(counts + 2 * N + r4.z, 1);
        k4.w = atomicAdd(counts + 3 * N + r4.w, 1);
        *(int4*)(rank + base) = k4;
    } else {
        for (int e = base; e < E; ++e)
            rank[e] = atomicAdd(counts + (size_t)(e & 3) * N + row[e], 1);
    }
}

// hist + conv_w fused (both depend only on inputs).
__global__ __launch_bounds__(256) void hist_conv_fused(
    const int* __restrict__ row, int* __restrict__ counts,
    int* __restrict__ rank, int N, int E,
    const float* __restrict__ W, unsigned short* __restrict__ Wt, int G_conv)
{
    const int bid = blockIdx.x;
    if (bid < G_conv) {
        const int idx = bid * 256 + threadIdx.x;
        if (idx >= CC * CC) return;
        const int k = idx >> 7;          // coalesced read of W[k][n]
        const int n = idx & 127;
        const unsigned int sw =
            ((unsigned)(2 * k) ^ (((unsigned)n & 7u) << 4)) >> 1;
        Wt[(size_t)n * 128 + sw] = f2bf(W[idx]);
        return;
    }
    hist_quad(row, counts, rank, N, E,
              ((bid - G_conv) * 256 + threadIdx.x) * 4);
}

// ---------------------------------------------------------------------------
// Decoupled-lookback scan: ONE kernel replaces reduce/scan/final. 196 blocks
// (<= 256 CUs -> all co-resident by capacity; preds have lower blockIdx and
// dispatch first). state[b] = flag(hi32: 1=partial,2=inclusive) | value(lo32),
// device-scope acquire/release (G16: cross-XCD needs agent scope).
// Emits replica bases: rbase[0]=exclusive row start (== offsets), rbase[q] =
// rbase[q-1] + count_{q-1}.
// ---------------------------------------------------------------------------
__global__ __launch_bounds__(256) void scan_lookback(
    const int* __restrict__ counts, unsigned long long* state,
    int* __restrict__ rbase, int N)
{
    __shared__ int s[256];
    __shared__ int sPrefix;
    const int t = threadIdx.x;
    const int b = blockIdx.x;
    const int idx = b * 256 + t;
    int c0 = 0, c1 = 0, c2 = 0, c3 = 0;
    if (idx < N) {
        c0 = counts[idx];
        c1 = counts[N + idx];
        c2 = counts[2 * N + idx];
        c3 = counts[3 * N + idx];
    }
    const int v = c0 + c1 + c2 + c3;
    s[t] = v;
    __syncthreads();
    #pragma unroll
    for (int off = 1; off < 256; off <<= 1) {
        const int a = s[t];
        const int u = (t >= off) ? s[t - off] : 0;
        __syncthreads();
        s[t] = a + u;
        __syncthreads();
    }
    const int incl  = s[t];      // inclusive scan of v within block
    const int total = s[255];

    if (t == 0) {
        unsigned long long p =
            ((unsigned long long)1 << 32) | (unsigned int)total;
        __hip_atomic_store(&state[b], p, __ATOMIC_RELEASE,
                           __HIP_MEMORY_SCOPE_AGENT);
        int prefix = 0;
        for (int pb = b - 1; pb >= 0; ) {
            unsigned long long sv;
            do {
                sv = __hip_atomic_load(&state[pb], __ATOMIC_ACQUIRE,
                                       __HIP_MEMORY_SCOPE_AGENT);
            } while ((sv >> 32) == 0);
            prefix += (int)(unsigned int)sv;
            if ((sv >> 32) == 2) break;   // inclusive prefix: done
            --pb;                          // partial: keep walking back
        }
        unsigned long long q =
            ((unsigned long long)2 << 32) | (unsigned int)(prefix + total);
        __hip_atomic_store(&state[b], q, __ATOMIC_RELEASE,
                           __HIP_MEMORY_SCOPE_AGENT);
        sPrefix = prefix;
    }
    __syncthreads();

    if (idx < N) {
        const int off = sPrefix + incl - v;   // exclusive row start
        rbase[idx]         = off;
        rbase[N + idx]     = off + c0;
        rbase[2 * N + idx] = off + c0 + c1;
        rbase[3 * N + idx] = off + c0 + c1 + c2;
    }
}

// ---- fill quad (atomic-free): pos = rbase[e&3][row] + rank[e] -------------
__device__ __forceinline__ void fill_quad(
    const int* __restrict__ row, const int* __restrict__ col,
    const float* __restrict__ Lr, const float* __restrict__ Li,
    const int* __restrict__ rbase, const int* __restrict__ rank,
    int4* __restrict__ meta, int N, int E, int base)
{
    if (base + 3 < E) {               // base%4==0 -> reps are exactly 0,1,2,3
        const int4   r4 = *(const int4*)(row + base);
        const int4   c4 = *(const int4*)(col + base);
        const float4 a4 = *(const float4*)(Lr + base);
        const float4 b4 = *(const float4*)(Li + base);
        const int4   k4 = *(const int4*)(rank + base);
        meta[rbase[r4.x] + k4.x] =
            make_int4(c4.x, __float_as_int(a4.x), __float_as_int(b4.x), 0);
        meta[rbase[N + r4.y] + k4.y] =
            make_int4(c4.y, __float_as_int(a4.y), __float_as_int(b4.y), 0);
        meta[rbase[2 * N + r4.z] + k4.z] =
            make_int4(c4.z, __float_as_int(a4.z), __float_as_int(b4.z), 0);
        meta[rbase[3 * N + r4.w] + k4.w] =
            make_int4(c4.w, __float_as_int(a4.w), __float_as_int(b4.w), 0);
    } else {
        for (int e = base; e < E; ++e)
            meta[rbase[(size_t)(e & 3) * N + row[e]] + rank[e]] =
                make_int4(col[e], __float_as_int(Lr[e]), __float_as_int(Li[e]), 0);
    }
}

// ---- gemm body (R8-R11 verified): Y = [Xr;Xi]@W via bf16 MFMA -------------
__device__ __forceinline__ void gemm_stage_B(
    const unsigned short* __restrict__ Wt, unsigned short* Bs, int t)
{
    const uint4* src = (const uint4*)Wt;
    uint4* dst = (uint4*)Bs;
    #pragma unroll
    for (int i = 0; i < 8; ++i) dst[t + 256 * i] = src[t + 256 * i];
}

__device__ __forceinline__ void gemm_tile(
    const float* __restrict__ Xr, const float* __restrict__ Xi,
    unsigned short* __restrict__ Y, int N, int bid,
    const unsigned short* Bs, unsigned short* As, int t)
{
    const int m0 = bid * 64;
    const int M = 2 * N;

    #pragma unroll
    for (int i = 0; i < 4; ++i) {
        const int blk = t + 256 * i;
        const int r  = blk >> 4;          // 0..63
        const int k0 = (blk & 15) * 8;    // 0..120
        const int m  = m0 + r;
        float4 q0 = make_float4(0.f, 0.f, 0.f, 0.f);
        float4 q1 = make_float4(0.f, 0.f, 0.f, 0.f);
        if (m < M) {
            const float* src = (m < N) ? (Xr + (size_t)m * CC)
                                       : (Xi + (size_t)(m - N) * CC);
            q0 = *(const float4*)(src + k0);
            q1 = *(const float4*)(src + k0 + 4);
        }
        uint4 h;
        h.x = pack2(q0.x, q0.y);
        h.y = pack2(q0.z, q0.w);
        h.z = pack2(q1.x, q1.y);
        h.w = pack2(q1.z, q1.w);
        const int byte = r * 256 + ((2 * k0) ^ ((r & 7) << 4));
        *(uint4*)((char*)As + byte) = h;
    }
    __syncthreads();

    const int w = t >> 6, lane = t & 63;
    const int wr = w >> 1, wc = w & 1;     // 2x2 wave grid
    const int r0 = wr * 32;
    const int c0 = wc * 64;
    const int lr = lane & 15;
    const int lk = lane >> 4;

    f32x4 acc[2][4];
    #pragma unroll
    for (int a = 0; a < 2; ++a)
        #pragma unroll
        for (int b = 0; b < 4; ++b)
            acc[a][b] = (f32x4){0.f, 0.f, 0.f, 0.f};

    #pragma unroll
    for (int kk = 0; kk < 4; ++kk) {
        const int kbase = kk * 32 + lk * 8;
        bf16x8 afrag[2];
        #pragma unroll
        for (int at = 0; at < 2; ++at) {
            const int row = r0 + at * 16 + lr;
            afrag[at] = *(const bf16x8*)((const char*)As +
                row * 256 + ((2 * kbase) ^ ((row & 7) << 4)));
        }
        #pragma unroll
        for (int bt = 0; bt < 4; ++bt) {
            const int col = c0 + bt * 16 + lr;
            const bf16x8 bfrag = *(const bf16x8*)((const char*)Bs +
                col * 256 + ((2 * kbase) ^ ((col & 7) << 4)));
            acc[0][bt] = __builtin_amdgcn_mfma_f32_16x16x32_bf16(
                afrag[0], bfrag, acc[0][bt], 0, 0, 0);
            acc[1][bt] = __builtin_amdgcn_mfma_f32_16x16x32_bf16(
                afrag[1], bfrag, acc[1][bt], 0, 0, 0);
        }
    }

    #pragma unroll
    for (int at = 0; at < 2; ++at) {
        #pragma unroll
        for (int v = 0; v < 4; ++v) {
            const int m = m0 + r0 + at * 16 + lk * 4 + v;
            if (m >= M) continue;
            const int node = (m < N) ? m : m - N;
            const int half = (m < N) ? 0 : 128;
            unsigned short* dst = Y + (size_t)node * 256 + half;
            #pragma unroll
            for (int bt = 0; bt < 4; ++bt)
                dst[c0 + bt * 16 + lr] = f2bf(acc[at][bt][v]);
        }
    }
}

// gemm blocks first (longest work starts earliest), then fill blocks.
__global__ __launch_bounds__(256) void fill_gemm_fused(
    const int* __restrict__ row, const int* __restrict__ col,
    const float* __restrict__ Lr, const float* __restrict__ Li,
    const int* __restrict__ rbase, const int* __restrict__ rank,
    int4* __restrict__ meta,
    const float* __restrict__ Xr, const float* __restrict__ Xi,
    const unsigned short* __restrict__ Wt, unsigned short* __restrict__ Y,
    int N, int E, int G_gemm)
{
    __shared__ char smem[49152];
    const int bid = blockIdx.x;
    if (bid < G_gemm) {
        unsigned short* Bs = (unsigned short*)smem;
        unsigned short* As = (unsigned short*)(smem + 32768);
        gemm_stage_B(Wt, Bs, threadIdx.x);
        gemm_tile(Xr, Xi, Y, N, bid, Bs, As, threadIdx.x);
    } else {
        fill_quad(row, col, Lr, Li, rbase, rank, meta, N, E,
                  ((bid - G_gemm) * 256 + threadIdx.x) * 4);
    }
}

// ===========================================================================
// Fused gather: out[n] = sum_e L_e * Ybf16[col_e] + X[n]  (complex),
// 1 wave/node, 2 ch/lane, 8-edge chunks. (verified, 74us)
// ===========================================================================
__device__ __forceinline__ void cmadd_bf(
    const int4 m, const unsigned int ur, const unsigned int ui,
    float2& aR, float2& aI)
{
    const float lr = __int_as_float(m.y);
    const float li = __int_as_float(m.z);
    const float yrx = __uint_as_float(ur << 16);
    const float yry = __uint_as_float(ur & 0xFFFF0000u);
    const float yix = __uint_as_float(ui << 16);
    const float yiy = __uint_as_float(ui & 0xFFFF0000u);
    aR.x += lr * yrx - li * yix;
    aR.y += lr * yry - li * yiy;
    aI.x += li * yrx + lr * yix;
    aI.y += li * yry + lr * yiy;
}

__device__ __forceinline__ void edge_acc(
    const int4 m, const unsigned short* __restrict__ Y,
    int lane, float2& aR, float2& aI)
{
    const unsigned short* b = Y + (size_t)m.x * 256 + 2 * lane;
    const unsigned int ur = *(const unsigned int*)(b);
    const unsigned int ui = *(const unsigned int*)(b + 128);
    cmadd_bf(m, ur, ui, aR, aI);
}

__global__ __launch_bounds__(256) void gather_fused(
    const unsigned short* __restrict__ Y,  // packed bf16 [N][256]
    const float* __restrict__ Xr, const float* __restrict__ Xi,
    const int* __restrict__ offsets, const int4* __restrict__ meta,
    float* __restrict__ out, int N, int E)
{
    const int n = blockIdx.x * 4 + (threadIdx.x >> 6);
    if (n >= N) return;
    const int lane = threadIdx.x & 63;
    const int start = offsets[n];
    const int end   = (n + 1 < N) ? offsets[n + 1] : E;
    const int Em1 = E - 1;

    // residual init
    float2 aR = *(const float2*)(Xr + (size_t)n * CC + 2 * lane);
    float2 aI = *(const float2*)(Xi + (size_t)n * CC + 2 * lane);

    int4 m0 = meta[min(start + 0, Em1)];
    int4 m1 = meta[min(start + 1, Em1)];
    int4 m2 = meta[min(start + 2, Em1)];
    int4 m3 = meta[min(start + 3, Em1)];
    int4 m4 = meta[min(start + 4, Em1)];
    int4 m5 = meta[min(start + 5, Em1)];
    int4 m6 = meta[min(start + 6, Em1)];
    int4 m7 = meta[min(start + 7, Em1)];

    int j = start;
    for (; j + 8 <= end; j += 8) {
        // prefetch next chunk's meta (wave-uniform)
        const int4 n0 = meta[min(j +  8, Em1)];
        const int4 n1 = meta[min(j +  9, Em1)];
        const int4 n2 = meta[min(j + 10, Em1)];
        const int4 n3 = meta[min(j + 11, Em1)];
        const int4 n4 = meta[min(j + 12, Em1)];
        const int4 n5 = meta[min(j + 13, Em1)];
        const int4 n6 = meta[min(j + 14, Em1)];
        const int4 n7 = meta[min(j + 15, Em1)];
        // 16 independent dword loads from 8 contiguous 512B rows
        const unsigned short* b0 = Y + (size_t)m0.x * 256 + 2 * lane;
        const unsigned short* b1 = Y + (size_t)m1.x * 256 + 2 * lane;
        const unsigned short* b2 = Y + (size_t)m2.x * 256 + 2 * lane;
        const unsigned short* b3 = Y + (size_t)m3.x * 256 + 2 * lane;
        const unsigned short* b4 = Y + (size_t)m4.x * 256 + 2 * lane;
        const unsigned short* b5 = Y + (size_t)m5.x * 256 + 2 * lane;
        const unsigned short* b6 = Y + (size_t)m6.x * 256 + 2 * lane;
        const unsigned short* b7 = Y + (size_t)m7.x * 256 + 2 * lane;
        const unsigned int ur0 = *(const unsigned int*)(b0);
        const unsigned int ui0 = *(const unsigned int*)(b0 + 128);
        const unsigned int ur1 = *(const unsigned int*)(b1);
        const unsigned int ui1 = *(const unsigned int*)(b1 + 128);
        const unsigned int ur2 = *(const unsigned int*)(b2);
        const unsigned int ui2 = *(const unsigned int*)(b2 + 128);
        const unsigned int ur3 = *(const unsigned int*)(b3);
        const unsigned int ui3 = *(const unsigned int*)(b3 + 128);
        const unsigned int ur4 = *(const unsigned int*)(b4);
        const unsigned int ui4 = *(const unsigned int*)(b4 + 128);
        const unsigned int ur5 = *(const unsigned int*)(b5);
        const unsigned int ui5 = *(const unsigned int*)(b5 + 128);
        const unsigned int ur6 = *(const unsigned int*)(b6);
        const unsigned int ui6 = *(const unsigned int*)(b6 + 128);
        const unsigned int ur7 = *(const unsigned int*)(b7);
        const unsigned int ui7 = *(const unsigned int*)(b7 + 128);

        cmadd_bf(m0, ur0, ui0, aR, aI);
        cmadd_bf(m1, ur1, ui1, aR, aI);
        cmadd_bf(m2, ur2, ui2, aR, aI);
        cmadd_bf(m3, ur3, ui3, aR, aI);
        cmadd_bf(m4, ur4, ui4, aR, aI);
        cmadd_bf(m5, ur5, ui5, aR, aI);
        cmadd_bf(m6, ur6, ui6, aR, aI);
        cmadd_bf(m7, ur7, ui7, aR, aI);

        m0 = n0; m1 = n1; m2 = n2; m3 = n3;
        m4 = n4; m5 = n5; m6 = n6; m7 = n7;
    }
    const int r = end - j;   // 0..7 remaining edges, meta already in m0..m6
    if (r > 0) edge_acc(m0, Y, lane, aR, aI);
    if (r > 1) edge_acc(m1, Y, lane, aR, aI);
    if (r > 2) edge_acc(m2, Y, lane, aR, aI);
    if (r > 3) edge_acc(m3, Y, lane, aR, aI);
    if (r > 4) edge_acc(m4, Y, lane, aR, aI);
    if (r > 5) edge_acc(m5, Y, lane, aR, aI);
    if (r > 6) edge_acc(m6, Y, lane, aR, aI);

    *(float2*)(out + (size_t)n * CC + 2 * lane) = aR;
    *(float2*)(out + ((size_t)n + N) * CC + 2 * lane) = aI;
}

// ===========================================================================
// Fallback kernels (fp32 paths for small workspaces)
// ===========================================================================
__global__ __launch_bounds__(256) void gather_nodes(
    const float* __restrict__ Xr, const float* __restrict__ Xi,
    const int* __restrict__ offsets, const int4* __restrict__ meta,
    float* __restrict__ out, int N, int E)
{
    const int n = blockIdx.x * 4 + (threadIdx.x >> 6);
    if (n >= N) return;
    const int lane = threadIdx.x & 63;
    const int start = offsets[n];
    const int end   = (n + 1 < N) ? offsets[n + 1] : E;
    float2 aR = make_float2(0.f, 0.f);
    float2 aI = make_float2(0.f, 0.f);
    for (int j = start; j < end; ++j) {
        const int4 m0 = meta[j];
        const float2 xr0 = *(const float2*)(Xr + (size_t)m0.x * CC + 2 * lane);
        const float2 xi0 = *(const float2*)(Xi + (size_t)m0.x * CC + 2 * lane);
        const float lr0 = __int_as_float(m0.y), li0 = __int_as_float(m0.z);
        aR.x += lr0 * xr0.x - li0 * xi0.x;
        aR.y += lr0 * xr0.y - li0 * xi0.y;
        aI.x += li0 * xr0.x + lr0 * xi0.x;
        aI.y += li0 * xr0.y + lr0 * xi0.y;
    }
    *(float2*)(out + (size_t)n * CC + 2 * lane) = aR;
    *(float2*)(out + ((size_t)n + N) * CC + 2 * lane) = aI;
}

__global__ __launch_bounds__(256) void scatter_edges(
    const float* __restrict__ Xr, const float* __restrict__ Xi,
    const float* __restrict__ Lr, const float* __restrict__ Li,
    const int* __restrict__ row, const int* __restrict__ col,
    float* __restrict__ out, int N, int E)
{
    const int e = blockIdx.x * 4 + (threadIdx.x >> 6);
    if (e >= E) return;
    const int lane = threadIdx.x & 63;
    const int r = row[e], c = col[e];
    const float lr = Lr[e];
    const float li = Li[e];
    const float2 xr = *(const float2*)(Xr + (size_t)c * CC + 2 * lane);
    const float2 xi = *(const float2*)(Xi + (size_t)c * CC + 2 * lane);
    float* pr = out + (size_t)r * CC + 2 * lane;
    float* pi = out + ((size_t)r + N) * CC + 2 * lane;
    unsafeAtomicAdd(pr,     lr * xr.x - li * xi.x);
    unsafeAtomicAdd(pr + 1, lr * xr.y - li * xi.y);
    unsafeAtomicAdd(pi,     li * xr.x + lr * xi.x);
    unsafeAtomicAdd(pi + 1, li * xr.y + lr * xi.y);
}

__global__ __launch_bounds__(256) void hist_rank_fb(
    const int* __restrict__ row, int* __restrict__ counts,
    int* __restrict__ rank, int N, int E)
{
    hist_quad(row, counts, rank, N, E,
              (blockIdx.x * 256 + threadIdx.x) * 4);
}

__global__ __launch_bounds__(256) void fill_csr_fb(
    const int* __restrict__ row, const int* __restrict__ col,
    const float* __restrict__ Lr, const float* __restrict__ Li,
    const int* __restrict__ rbase, const int* __restrict__ rank,
    int4* __restrict__ meta, int N, int E)
{
    fill_quad(row, col, Lr, Li, rbase, rank, meta, N, E,
              (blockIdx.x * 256 + threadIdx.x) * 4);
}

__global__ __launch_bounds__(256) void gemm_inplace(
    float* __restrict__ io, const float* __restrict__ W,
    const float* __restrict__ Xp, int N)
{
    __shared__ float Ws[64 * CC];
    __shared__ float AsT[CC][36];
    const int t = threadIdx.x;
    const int m0 = blockIdx.x * 32;

    for (int ch = t; ch < 1024; ch += 256) {
        const int r  = ch >> 5;
        const int k0 = (ch & 31) * 4;
        const int m  = m0 + r;
        float4 q = make_float4(0.f, 0.f, 0.f, 0.f);
        if (m < N) q = *(const float4*)(io + (size_t)m * CC + k0);
        AsT[k0 + 0][r] = q.x;
        AsT[k0 + 1][r] = q.y;
        AsT[k0 + 2][r] = q.z;
        AsT[k0 + 3][r] = q.w;
    }

    const int cg_ = t & 31;
    const int rs = t >> 5;
    float s[4][4];
    #pragma unroll
    for (int a = 0; a < 4; ++a)
        #pragma unroll
        for (int b = 0; b < 4; ++b) s[a][b] = 0.f;

    for (int kc = 0; kc < 2; ++kc) {
        __syncthreads();
        {
            const float4* src = (const float4*)(W + (size_t)kc * 64 * CC);
            float4* dst = (float4*)Ws;
            #pragma unroll
            for (int i = 0; i < 8; ++i) dst[t + 256 * i] = src[t + 256 * i];
        }
        __syncthreads();
        #pragma unroll 4
        for (int kk = 0; kk < 64; ++kk) {
            const int k = kc * 64 + kk;
            const float4 av = *(const float4*)&AsT[k][rs * 4];
            const float4 wv = *(const float4*)&Ws[kk * CC + cg_ * 4];
            const float ar[4] = {av.x, av.y, av.z, av.w};
            const float wc[4] = {wv.x, wv.y, wv.z, wv.w};
            #pragma unroll
            for (int a = 0; a < 4; ++a)
                #pragma unroll
                for (int b = 0; b < 4; ++b) s[a][b] += ar[a] * wc[b];
        }
    }

    #pragma unroll
    for (int a = 0; a < 4; ++a) {
        const int m = m0 + rs * 4 + a;
        if (m >= N) continue;
        const float4 xv = *(const float4*)(Xp + (size_t)m * CC + cg_ * 4);
        float4 o;
        o.x = s[a][0] + xv.x;
        o.y = s[a][1] + xv.y;
        o.z = s[a][2] + xv.z;
        o.w = s[a][3] + xv.w;
        *(float4*)(io + (size_t)m * CC + cg_ * 4) = o;
    }
}

// ===========================================================================
extern "C" void kernel_launch(void* const* d_in, const int* in_sizes, int n_in,
                              void* d_out, int out_size, void* d_ws, size_t ws_size,
                              hipStream_t stream)
{
    const float* Xr = (const float*)d_in[0];
    const float* Xi = (const float*)d_in[1];
    const float* Lr = (const float*)d_in[2];
    const float* Li = (const float*)d_in[3];
    const float* W  = (const float*)d_in[4];
    const int* row = (const int*)d_in[5];
    const int* col = (const int*)d_in[6];
    float* out = (float*)d_out;

    const int N = in_sizes[0] / CC;     // 50000
    const int E = in_sizes[2];          // 800000
    const int NB = (N + 255) / 256;     // scan blocks (196 <= 256 CUs)
    const int EB4 = ((E + 3) / 4 + 255) / 256;
    const int G_conv = (CC * CC + 255) / 256;   // 64
    const int G_gemm = (2 * N + 63) / 64;       // 1563

    const size_t y_bytes    = (size_t)N * 256 * sizeof(unsigned short);
    const size_t wt_bytes   = (size_t)CC * CC * sizeof(unsigned short);
    const size_t meta_bytes = (size_t)E * 16;
    // counts[4N] + state[256](ull) + rbase[4N] + rank[E]
    const size_t int_bytes  = (size_t)4 * N * 4 + 256 * 8
                            + (size_t)4 * N * 4 + (size_t)E * 4;
    const size_t need_csr   = meta_bytes + int_bytes;
    const size_t need_fused = y_bytes + wt_bytes + need_csr;

    if (ws_size >= need_fused) {
        unsigned short* Y  = (unsigned short*)d_ws;
        unsigned short* Wt = (unsigned short*)((char*)d_ws + y_bytes);
        int4*  meta   = (int4*)((char*)d_ws + y_bytes + wt_bytes);
        int*   counts = (int*)((char*)d_ws + y_bytes + wt_bytes + meta_bytes);
        unsigned long long* state = (unsigned long long*)(counts + 4 * N);
        int*   rbase  = (int*)(state + 256);
        int*   rank   = rbase + 4 * N;

        // zero counts AND lookback state in one memset (contiguous)
        hipMemsetAsync(counts, 0, (size_t)4 * N * sizeof(int) + 256 * 8, stream);
        hist_conv_fused<<<dim3(G_conv + EB4), dim3(256), 0, stream>>>(
            row, counts, rank, N, E, W, Wt, G_conv);
        scan_lookback<<<dim3(NB), dim3(256), 0, stream>>>(
            counts, state, rbase, N);
        fill_gemm_fused<<<dim3(G_gemm + EB4), dim3(256), 0, stream>>>(
            row, col, Lr, Li, rbase, rank, meta, Xr, Xi, Wt, Y, N, E, G_gemm);
        gather_fused<<<dim3((N + 3) / 4), dim3(256), 0, stream>>>(
            Y, Xr, Xi, rbase /* == offsets */, meta, out, N, E);
    } else if (ws_size >= need_csr) {
        int4* meta    = (int4*)d_ws;
        int*  counts  = (int*)((char*)d_ws + meta_bytes);
        unsigned long long* state = (unsigned long long*)(counts + 4 * N);
        int*  rbase   = (int*)(state + 256);
        int*  rank    = rbase + 4 * N;

        hipMemsetAsync(counts, 0, (size_t)4 * N * sizeof(int) + 256 * 8, stream);
        hist_rank_fb<<<dim3(EB4), dim3(256), 0, stream>>>(row, counts, rank, N, E);
        scan_lookback<<<dim3(NB), dim3(256), 0, stream>>>(
            counts, state, rbase, N);
        fill_csr_fb<<<dim3(EB4), dim3(256), 0, stream>>>(
            row, col, Lr, Li, rbase, rank, meta, N, E);
        gather_nodes<<<dim3((N + 3) / 4), dim3(256), 0, stream>>>(
            Xr, Xi, rbase, meta, out, N, E);
        gemm_inplace<<<dim3((N + 31) / 32), dim3(256), 0, stream>>>(out, W, Xr, N);
        gemm_inplace<<<dim3((N + 31) / 32), dim3(256), 0, stream>>>(
            out + (size_t)N * CC, W, Xi, N);
    } else {
        hipMemsetAsync(out, 0, (size_t)2 * N * CC * sizeof(float), stream);
        scatter_edges<<<dim3((E + 3) / 4), dim3(256), 0, stream>>>(
            Xr, Xi, Lr, Li, row, col, out, N, E);
        gemm_inplace<<<dim3((N + 31) / 32), dim3(256), 0, stream>>>(out, W, Xr, N);
        gemm_inplace<<<dim3((N + 31) / 32), dim3(256), 0, stream>>>(
            out + (size_t)N * CC, W, Xi, N);
    }
}

// Round 15
// 249.917 us; speedup vs baseline: 2.1513x; 1.1338x over previous
//
#include <hip/hip_runtime.h>
#include <cstddef>

#define CC 128  // channels

typedef __attribute__((ext_vector_type(8))) short bf16x8;
typedef __attribute__((ext_vector_type(4))) float f32x4;

// fp32 -> bf16 (round-to-nearest-even on the bit pattern)
__device__ __forceinline__ unsigned short f2bf(float f)
{
    unsigned int u = __float_as_uint(f);
    u = (u + 0x7fffu + ((u >> 16) & 1u)) >> 16;
    return (unsigned short)u;
}

__device__ __forceinline__ unsigned int pack2(float a, float b)
{
    return (unsigned int)f2bf(a) | ((unsigned int)f2bf(b) << 16);
}

// ===========================================================================
// Structure (R15): [gemm||hist proportional-interleaved] -> 3-kernel scan ->
// fill -> gather.
// R12: coop grid.sync on 8 non-coherent XCDs = 2.6x slower. R13: lookback
// scan (serial agent-scope acquire walk) = +36us. R14 BUG: hardcoded 1:2
// role ratio assumed EB4=3125 but EB4=782 -> half the gemm tiles never ran.
// Fix: proportional assignment (exactly G_gemm gemm + EB4 hist blocks for
// ANY split, telescoping-sum proof in q/hb derivation below).
// ===========================================================================

// ---- hist quad: 4-bank counts + rank = atomicAdd return -------------------
__device__ __forceinline__ void hist_quad(
    const int* __restrict__ row, int* __restrict__ counts,
    int* __restrict__ rank, int N, int E, int base)
{
    if (base + 3 < E) {
        const int4 r4 = *(const int4*)(row + base);
        int4 k4;
        k4.x = atomicAdd(counts + 0 * N + r4.x, 1);
        k4.y = atomicAdd(counts + 1 * N + r4.y, 1);
        k4.z = atomicAdd(counts + 2 * N + r4.z, 1);
        k4.w = atomicAdd(counts + 3 * N + r4.w, 1);
        *(int4*)(rank + base) = k4;
    } else {
        for (int e = base; e < E; ++e)
            rank[e] = atomicAdd(counts + (size_t)(e & 3) * N + row[e], 1);
    }
}

// ---- gemm: stage Bs (bf16, XOR-swizzled) directly from fp32 W -------------
// W[k][n] row-major, 64KB -> L2-resident after first block. Byte layout
// identical to the R8-R11 verified Wt: byte(n,k) = n*256 + ((2k)^((n&7)<<4)).
// XOR mask only touches bits 4-6, so 16B-aligned fragment reads remain
// contiguous-in-k (same proof as the A-tile swizzle).
__device__ __forceinline__ void gemm_stage_B_from_W(
    const float* __restrict__ W, unsigned short* Bs, int t)
{
    #pragma unroll
    for (int i = 0; i < 16; ++i) {
        const int idx4 = (t + 256 * i) * 4;   // 4 consecutive n, same k
        const int k  = idx4 >> 7;
        const int n0 = idx4 & 127;
        const float4 w4 = *(const float4*)(W + idx4);
        *(unsigned short*)((char*)Bs + (n0 + 0) * 256 +
            ((2 * k) ^ (((n0 + 0) & 7) << 4))) = f2bf(w4.x);
        *(unsigned short*)((char*)Bs + (n0 + 1) * 256 +
            ((2 * k) ^ (((n0 + 1) & 7) << 4))) = f2bf(w4.y);
        *(unsigned short*)((char*)Bs + (n0 + 2) * 256 +
            ((2 * k) ^ (((n0 + 2) & 7) << 4))) = f2bf(w4.z);
        *(unsigned short*)((char*)Bs + (n0 + 3) * 256 +
            ((2 * k) ^ (((n0 + 3) & 7) << 4))) = f2bf(w4.w);
    }
}

// ---- gemm tile body (R8-R11 verified math): Y = [Xr;Xi]@W, bf16 MFMA ------
__device__ __forceinline__ void gemm_tile(
    const float* __restrict__ Xr, const float* __restrict__ Xi,
    unsigned short* __restrict__ Y, int N, int bid,
    const unsigned short* Bs, unsigned short* As, int t)
{
    const int m0 = bid * 64;
    const int M = 2 * N;

    #pragma unroll
    for (int i = 0; i < 4; ++i) {
        const int blk = t + 256 * i;
        const int r  = blk >> 4;          // 0..63
        const int k0 = (blk & 15) * 8;    // 0..120
        const int m  = m0 + r;
        float4 q0 = make_float4(0.f, 0.f, 0.f, 0.f);
        float4 q1 = make_float4(0.f, 0.f, 0.f, 0.f);
        if (m < M) {
            const float* src = (m < N) ? (Xr + (size_t)m * CC)
                                       : (Xi + (size_t)(m - N) * CC);
            q0 = *(const float4*)(src + k0);
            q1 = *(const float4*)(src + k0 + 4);
        }
        uint4 h;
        h.x = pack2(q0.x, q0.y);
        h.y = pack2(q0.z, q0.w);
        h.z = pack2(q1.x, q1.y);
        h.w = pack2(q1.z, q1.w);
        const int byte = r * 256 + ((2 * k0) ^ ((r & 7) << 4));
        *(uint4*)((char*)As + byte) = h;
    }
    __syncthreads();   // covers both Bs and As staging

    const int w = t >> 6, lane = t & 63;
    const int wr = w >> 1, wc = w & 1;     // 2x2 wave grid
    const int r0 = wr * 32;
    const int c0 = wc * 64;
    const int lr = lane & 15;
    const int lk = lane >> 4;

    f32x4 acc[2][4];
    #pragma unroll
    for (int a = 0; a < 2; ++a)
        #pragma unroll
        for (int b = 0; b < 4; ++b)
            acc[a][b] = (f32x4){0.f, 0.f, 0.f, 0.f};

    #pragma unroll
    for (int kk = 0; kk < 4; ++kk) {
        const int kbase = kk * 32 + lk * 8;
        bf16x8 afrag[2];
        #pragma unroll
        for (int at = 0; at < 2; ++at) {
            const int row = r0 + at * 16 + lr;
            afrag[at] = *(const bf16x8*)((const char*)As +
                row * 256 + ((2 * kbase) ^ ((row & 7) << 4)));
        }
        #pragma unroll
        for (int bt = 0; bt < 4; ++bt) {
            const int col = c0 + bt * 16 + lr;
            const bf16x8 bfrag = *(const bf16x8*)((const char*)Bs +
                col * 256 + ((2 * kbase) ^ ((col & 7) << 4)));
            acc[0][bt] = __builtin_amdgcn_mfma_f32_16x16x32_bf16(
                afrag[0], bfrag, acc[0][bt], 0, 0, 0);
            acc[1][bt] = __builtin_amdgcn_mfma_f32_16x16x32_bf16(
                afrag[1], bfrag, acc[1][bt], 0, 0, 0);
        }
    }

    #pragma unroll
    for (int at = 0; at < 2; ++at) {
        #pragma unroll
        for (int v = 0; v < 4; ++v) {
            const int m = m0 + r0 + at * 16 + lk * 4 + v;
            if (m >= M) continue;
            const int node = (m < N) ? m : m - N;
            const int half = (m < N) ? 0 : 128;
            unsigned short* dst = Y + (size_t)node * 256 + half;
            #pragma unroll
            for (int bt = 0; bt < 4; ++bt)
                dst[c0 + bt * 16 + lr] = f2bf(acc[at][bt][v]);
        }
    }
}

// Fused gemm||hist with PROPORTIONAL role assignment:
// block bid is gemm iff floor((bid+1)*Gg/total) > floor(bid*Gg/total);
// gemm index q = floor(bid*Gg/total); hist index hb = bid - q.
// Telescoping: exactly Gg gemm blocks (q = 0..Gg-1) and total-Gg hist
// blocks (hb = 0..EB4-1), evenly interleaved, for ANY Gg:EB4 ratio.
__global__ __launch_bounds__(256) void gemm_hist_fused(
    const float* __restrict__ Xr, const float* __restrict__ Xi,
    const float* __restrict__ W, unsigned short* __restrict__ Y,
    const int* __restrict__ row, int* __restrict__ counts,
    int* __restrict__ rank, int N, int E, int G_gemm, int total)
{
    __shared__ char smem[49152];
    const int bid = blockIdx.x;
    const long long pg  = (long long)bid * G_gemm / total;
    const long long pg1 = (long long)(bid + 1) * G_gemm / total;
    if (pg1 > pg) {
        unsigned short* Bs = (unsigned short*)smem;
        unsigned short* As = (unsigned short*)(smem + 32768);
        gemm_stage_B_from_W(W, Bs, threadIdx.x);
        gemm_tile(Xr, Xi, Y, N, (int)pg, Bs, As, threadIdx.x);
    } else {
        const int hb = bid - (int)pg;
        hist_quad(row, counts, rank, N, E, (hb * 256 + threadIdx.x) * 4);
    }
}

// ---------------------------------------------------------------------------
// 3-kernel scan (R11-verified; R13's lookback regressed +36us)
// ---------------------------------------------------------------------------
__global__ __launch_bounds__(256) void scan_block_reduce(
    const int* __restrict__ counts, int* __restrict__ bsum, int N)
{
    __shared__ int s[256];
    const int t = threadIdx.x;
    const int idx = blockIdx.x * 256 + t;
    int v = 0;
    if (idx < N)
        v = counts[idx] + counts[N + idx] + counts[2 * N + idx]
          + counts[3 * N + idx];
    s[t] = v;
    __syncthreads();
    #pragma unroll
    for (int off = 128; off > 0; off >>= 1) {
        if (t < off) s[t] += s[t + off];
        __syncthreads();
    }
    if (t == 0) bsum[blockIdx.x] = s[0];
}

__global__ __launch_bounds__(256) void scan_bsum(
    const int* __restrict__ bsum, int* __restrict__ bpre, int NB)
{
    __shared__ int s[256];
    const int t = threadIdx.x;
    s[t] = (t < NB) ? bsum[t] : 0;
    __syncthreads();
    #pragma unroll
    for (int off = 1; off < 256; off <<= 1) {
        const int v = s[t];
        const int u = (t >= off) ? s[t - off] : 0;
        __syncthreads();
        s[t] = v + u;
        __syncthreads();
    }
    if (t < NB) bpre[t] = t ? s[t - 1] : 0;
}

__global__ __launch_bounds__(256) void scan_final(
    const int* __restrict__ counts, const int* __restrict__ bpre,
    int* __restrict__ rbase, int N)
{
    __shared__ int s[256];
    const int t = threadIdx.x;
    const int idx = blockIdx.x * 256 + t;
    int c0 = 0, c1 = 0, c2 = 0, c3 = 0;
    if (idx < N) {
        c0 = counts[idx];
        c1 = counts[N + idx];
        c2 = counts[2 * N + idx];
        c3 = counts[3 * N + idx];
    }
    const int v = c0 + c1 + c2 + c3;
    s[t] = v;
    __syncthreads();
    #pragma unroll
    for (int off = 1; off < 256; off <<= 1) {
        const int a = s[t];
        const int u = (t >= off) ? s[t - off] : 0;
        __syncthreads();
        s[t] = a + u;
        __syncthreads();
    }
    if (idx < N) {
        const int off = bpre[blockIdx.x] + s[t] - v;  // exclusive row start
        rbase[idx]         = off;
        rbase[N + idx]     = off + c0;
        rbase[2 * N + idx] = off + c0 + c1;
        rbase[3 * N + idx] = off + c0 + c1 + c2;
    }
}

// ---- fill quad (atomic-free): pos = rbase[e&3][row] + rank[e] -------------
__device__ __forceinline__ void fill_quad(
    const int* __restrict__ row, const int* __restrict__ col,
    const float* __restrict__ Lr, const float* __restrict__ Li,
    const int* __restrict__ rbase, const int* __restrict__ rank,
    int4* __restrict__ meta, int N, int E, int base)
{
    if (base + 3 < E) {               // base%4==0 -> reps are exactly 0,1,2,3
        const int4   r4 = *(const int4*)(row + base);
        const int4   c4 = *(const int4*)(col + base);
        const float4 a4 = *(const float4*)(Lr + base);
        const float4 b4 = *(const float4*)(Li + base);
        const int4   k4 = *(const int4*)(rank + base);
        meta[rbase[r4.x] + k4.x] =
            make_int4(c4.x, __float_as_int(a4.x), __float_as_int(b4.x), 0);
        meta[rbase[N + r4.y] + k4.y] =
            make_int4(c4.y, __float_as_int(a4.y), __float_as_int(b4.y), 0);
        meta[rbase[2 * N + r4.z] + k4.z] =
            make_int4(c4.z, __float_as_int(a4.z), __float_as_int(b4.z), 0);
        meta[rbase[3 * N + r4.w] + k4.w] =
            make_int4(c4.w, __float_as_int(a4.w), __float_as_int(b4.w), 0);
    } else {
        for (int e = base; e < E; ++e)
            meta[rbase[(size_t)(e & 3) * N + row[e]] + rank[e]] =
                make_int4(col[e], __float_as_int(Lr[e]), __float_as_int(Li[e]), 0);
    }
}

__global__ __launch_bounds__(256) void fill_csr_rank(
    const int* __restrict__ row, const int* __restrict__ col,
    const float* __restrict__ Lr, const float* __restrict__ Li,
    const int* __restrict__ rbase, const int* __restrict__ rank,
    int4* __restrict__ meta, int N, int E)
{
    fill_quad(row, col, Lr, Li, rbase, rank, meta, N, E,
              (blockIdx.x * 256 + threadIdx.x) * 4);
}

// ===========================================================================
// Fused gather: out[n] = sum_e L_e * Ybf16[col_e] + X[n]  (complex),
// 1 wave/node, 2 ch/lane, 8-edge chunks. (verified, 74us)
// ===========================================================================
__device__ __forceinline__ void cmadd_bf(
    const int4 m, const unsigned int ur, const unsigned int ui,
    float2& aR, float2& aI)
{
    const float lr = __int_as_float(m.y);
    const float li = __int_as_float(m.z);
    const float yrx = __uint_as_float(ur << 16);
    const float yry = __uint_as_float(ur & 0xFFFF0000u);
    const float yix = __uint_as_float(ui << 16);
    const float yiy = __uint_as_float(ui & 0xFFFF0000u);
    aR.x += lr * yrx - li * yix;
    aR.y += lr * yry - li * yiy;
    aI.x += li * yrx + lr * yix;
    aI.y += li * yry + lr * yiy;
}

__device__ __forceinline__ void edge_acc(
    const int4 m, const unsigned short* __restrict__ Y,
    int lane, float2& aR, float2& aI)
{
    const unsigned short* b = Y + (size_t)m.x * 256 + 2 * lane;
    const unsigned int ur = *(const unsigned int*)(b);
    const unsigned int ui = *(const unsigned int*)(b + 128);
    cmadd_bf(m, ur, ui, aR, aI);
}

__global__ __launch_bounds__(256) void gather_fused(
    const unsigned short* __restrict__ Y,  // packed bf16 [N][256]
    const float* __restrict__ Xr, const float* __restrict__ Xi,
    const int* __restrict__ offsets, const int4* __restrict__ meta,
    float* __restrict__ out, int N, int E)
{
    const int n = blockIdx.x * 4 + (threadIdx.x >> 6);
    if (n >= N) return;
    const int lane = threadIdx.x & 63;
    const int start = offsets[n];
    const int end   = (n + 1 < N) ? offsets[n + 1] : E;
    const int Em1 = E - 1;

    // residual init
    float2 aR = *(const float2*)(Xr + (size_t)n * CC + 2 * lane);
    float2 aI = *(const float2*)(Xi + (size_t)n * CC + 2 * lane);

    int4 m0 = meta[min(start + 0, Em1)];
    int4 m1 = meta[min(start + 1, Em1)];
    int4 m2 = meta[min(start + 2, Em1)];
    int4 m3 = meta[min(start + 3, Em1)];
    int4 m4 = meta[min(start + 4, Em1)];
    int4 m5 = meta[min(start + 5, Em1)];
    int4 m6 = meta[min(start + 6, Em1)];
    int4 m7 = meta[min(start + 7, Em1)];

    int j = start;
    for (; j + 8 <= end; j += 8) {
        // prefetch next chunk's meta (wave-uniform)
        const int4 n0 = meta[min(j +  8, Em1)];
        const int4 n1 = meta[min(j +  9, Em1)];
        const int4 n2 = meta[min(j + 10, Em1)];
        const int4 n3 = meta[min(j + 11, Em1)];
        const int4 n4 = meta[min(j + 12, Em1)];
        const int4 n5 = meta[min(j + 13, Em1)];
        const int4 n6 = meta[min(j + 14, Em1)];
        const int4 n7 = meta[min(j + 15, Em1)];
        // 16 independent dword loads from 8 contiguous 512B rows
        const unsigned short* b0 = Y + (size_t)m0.x * 256 + 2 * lane;
        const unsigned short* b1 = Y + (size_t)m1.x * 256 + 2 * lane;
        const unsigned short* b2 = Y + (size_t)m2.x * 256 + 2 * lane;
        const unsigned short* b3 = Y + (size_t)m3.x * 256 + 2 * lane;
        const unsigned short* b4 = Y + (size_t)m4.x * 256 + 2 * lane;
        const unsigned short* b5 = Y + (size_t)m5.x * 256 + 2 * lane;
        const unsigned short* b6 = Y + (size_t)m6.x * 256 + 2 * lane;
        const unsigned short* b7 = Y + (size_t)m7.x * 256 + 2 * lane;
        const unsigned int ur0 = *(const unsigned int*)(b0);
        const unsigned int ui0 = *(const unsigned int*)(b0 + 128);
        const unsigned int ur1 = *(const unsigned int*)(b1);
        const unsigned int ui1 = *(const unsigned int*)(b1 + 128);
        const unsigned int ur2 = *(const unsigned int*)(b2);
        const unsigned int ui2 = *(const unsigned int*)(b2 + 128);
        const unsigned int ur3 = *(const unsigned int*)(b3);
        const unsigned int ui3 = *(const unsigned int*)(b3 + 128);
        const unsigned int ur4 = *(const unsigned int*)(b4);
        const unsigned int ui4 = *(const unsigned int*)(b4 + 128);
        const unsigned int ur5 = *(const unsigned int*)(b5);
        const unsigned int ui5 = *(const unsigned int*)(b5 + 128);
        const unsigned int ur6 = *(const unsigned int*)(b6);
        const unsigned int ui6 = *(const unsigned int*)(b6 + 128);
        const unsigned int ur7 = *(const unsigned int*)(b7);
        const unsigned int ui7 = *(const unsigned int*)(b7 + 128);

        cmadd_bf(m0, ur0, ui0, aR, aI);
        cmadd_bf(m1, ur1, ui1, aR, aI);
        cmadd_bf(m2, ur2, ui2, aR, aI);
        cmadd_bf(m3, ur3, ui3, aR, aI);
        cmadd_bf(m4, ur4, ui4, aR, aI);
        cmadd_bf(m5, ur5, ui5, aR, aI);
        cmadd_bf(m6, ur6, ui6, aR, aI);
        cmadd_bf(m7, ur7, ui7, aR, aI);

        m0 = n0; m1 = n1; m2 = n2; m3 = n3;
        m4 = n4; m5 = n5; m6 = n6; m7 = n7;
    }
    const int r = end - j;   // 0..7 remaining edges, meta already in m0..m6
    if (r > 0) edge_acc(m0, Y, lane, aR, aI);
    if (r > 1) edge_acc(m1, Y, lane, aR, aI);
    if (r > 2) edge_acc(m2, Y, lane, aR, aI);
    if (r > 3) edge_acc(m3, Y, lane, aR, aI);
    if (r > 4) edge_acc(m4, Y, lane, aR, aI);
    if (r > 5) edge_acc(m5, Y, lane, aR, aI);
    if (r > 6) edge_acc(m6, Y, lane, aR, aI);

    *(float2*)(out + (size_t)n * CC + 2 * lane) = aR;
    *(float2*)(out + ((size_t)n + N) * CC + 2 * lane) = aI;
}

// ===========================================================================
// Fallback kernels (fp32 paths for small workspaces)
// ===========================================================================
__global__ __launch_bounds__(256) void hist_rank_fb(
    const int* __restrict__ row, int* __restrict__ counts,
    int* __restrict__ rank, int N, int E)
{
    hist_quad(row, counts, rank, N, E,
              (blockIdx.x * 256 + threadIdx.x) * 4);
}

__global__ __launch_bounds__(256) void gather_nodes(
    const float* __restrict__ Xr, const float* __restrict__ Xi,
    const int* __restrict__ offsets, const int4* __restrict__ meta,
    float* __restrict__ out, int N, int E)
{
    const int n = blockIdx.x * 4 + (threadIdx.x >> 6);
    if (n >= N) return;
    const int lane = threadIdx.x & 63;
    const int start = offsets[n];
    const int end   = (n + 1 < N) ? offsets[n + 1] : E;
    float2 aR = make_float2(0.f, 0.f);
    float2 aI = make_float2(0.f, 0.f);
    for (int j = start; j < end; ++j) {
        const int4 m0 = meta[j];
        const float2 xr0 = *(const float2*)(Xr + (size_t)m0.x * CC + 2 * lane);
        const float2 xi0 = *(const float2*)(Xi + (size_t)m0.x * CC + 2 * lane);
        const float lr0 = __int_as_float(m0.y), li0 = __int_as_float(m0.z);
        aR.x += lr0 * xr0.x - li0 * xi0.x;
        aR.y += lr0 * xr0.y - li0 * xi0.y;
        aI.x += li0 * xr0.x + lr0 * xi0.x;
        aI.y += li0 * xr0.y + lr0 * xi0.y;
    }
    *(float2*)(out + (size_t)n * CC + 2 * lane) = aR;
    *(float2*)(out + ((size_t)n + N) * CC + 2 * lane) = aI;
}

__global__ __launch_bounds__(256) void scatter_edges(
    const float* __restrict__ Xr, const float* __restrict__ Xi,
    const float* __restrict__ Lr, const float* __restrict__ Li,
    const int* __restrict__ row, const int* __restrict__ col,
    float* __restrict__ out, int N, int E)
{
    const int e = blockIdx.x * 4 + (threadIdx.x >> 6);
    if (e >= E) return;
    const int lane = threadIdx.x & 63;
    const int r = row[e], c = col[e];
    const float lr = Lr[e];
    const float li = Li[e];
    const float2 xr = *(const float2*)(Xr + (size_t)c * CC + 2 * lane);
    const float2 xi = *(const float2*)(Xi + (size_t)c * CC + 2 * lane);
    float* pr = out + (size_t)r * CC + 2 * lane;
    float* pi = out + ((size_t)r + N) * CC + 2 * lane;
    unsafeAtomicAdd(pr,     lr * xr.x - li * xi.x);
    unsafeAtomicAdd(pr + 1, lr * xr.y - li * xi.y);
    unsafeAtomicAdd(pi,     li * xr.x + lr * xi.x);
    unsafeAtomicAdd(pi + 1, li * xr.y + lr * xi.y);
}

__global__ __launch_bounds__(256) void gemm_inplace(
    float* __restrict__ io, const float* __restrict__ W,
    const float* __restrict__ Xp, int N)
{
    __shared__ float Ws[64 * CC];
    __shared__ float AsT[CC][36];
    const int t = threadIdx.x;
    const int m0 = blockIdx.x * 32;

    for (int ch = t; ch < 1024; ch += 256) {
        const int r  = ch >> 5;
        const int k0 = (ch & 31) * 4;
        const int m  = m0 + r;
        float4 q = make_float4(0.f, 0.f, 0.f, 0.f);
        if (m < N) q = *(const float4*)(io + (size_t)m * CC + k0);
        AsT[k0 + 0][r] = q.x;
        AsT[k0 + 1][r] = q.y;
        AsT[k0 + 2][r] = q.z;
        AsT[k0 + 3][r] = q.w;
    }

    const int cg_ = t & 31;
    const int rs = t >> 5;
    float s[4][4];
    #pragma unroll
    for (int a = 0; a < 4; ++a)
        #pragma unroll
        for (int b = 0; b < 4; ++b) s[a][b] = 0.f;

    for (int kc = 0; kc < 2; ++kc) {
        __syncthreads();
        {
            const float4* src = (const float4*)(W + (size_t)kc * 64 * CC);
            float4* dst = (float4*)Ws;
            #pragma unroll
            for (int i = 0; i < 8; ++i) dst[t + 256 * i] = src[t + 256 * i];
        }
        __syncthreads();
        #pragma unroll 4
        for (int kk = 0; kk < 64; ++kk) {
            const int k = kc * 64 + kk;
            const float4 av = *(const float4*)&AsT[k][rs * 4];
            const float4 wv = *(const float4*)&Ws[kk * CC + cg_ * 4];
            const float ar[4] = {av.x, av.y, av.z, av.w};
            const float wc[4] = {wv.x, wv.y, wv.z, wv.w};
            #pragma unroll
            for (int a = 0; a < 4; ++a)
                #pragma unroll
                for (int b = 0; b < 4; ++b) s[a][b] += ar[a] * wc[b];
        }
    }

    #pragma unroll
    for (int a = 0; a < 4; ++a) {
        const int m = m0 + rs * 4 + a;
        if (m >= N) continue;
        const float4 xv = *(const float4*)(Xp + (size_t)m * CC + cg_ * 4);
        float4 o;
        o.x = s[a][0] + xv.x;
        o.y = s[a][1] + xv.y;
        o.z = s[a][2] + xv.z;
        o.w = s[a][3] + xv.w;
        *(float4*)(io + (size_t)m * CC + cg_ * 4) = o;
    }
}

// ===========================================================================
extern "C" void kernel_launch(void* const* d_in, const int* in_sizes, int n_in,
                              void* d_out, int out_size, void* d_ws, size_t ws_size,
                              hipStream_t stream)
{
    const float* Xr = (const float*)d_in[0];
    const float* Xi = (const float*)d_in[1];
    const float* Lr = (const float*)d_in[2];
    const float* Li = (const float*)d_in[3];
    const float* W  = (const float*)d_in[4];
    const int* row = (const int*)d_in[5];
    const int* col = (const int*)d_in[6];
    float* out = (float*)d_out;

    const int N = in_sizes[0] / CC;     // 50000
    const int E = in_sizes[2];          // 800000
    const int NB = (N + 255) / 256;     // scan blocks (196)
    const int EB4 = ((E + 3) / 4 + 255) / 256;  // 782 (4-edge/thread grid)
    const int G_gemm = (2 * N + 63) / 64;       // 1563
    const int G_total = G_gemm + EB4;           // 2345

    const size_t y_bytes    = (size_t)N * 256 * sizeof(unsigned short);
    const size_t meta_bytes = (size_t)E * 16;
    // counts[4N] + rbase[4N] + bsum/bpre[512] + rank[E]
    const size_t int_bytes  = ((size_t)8 * N + 512 + E) * sizeof(int);
    const size_t need_csr   = meta_bytes + int_bytes;
    const size_t need_fused = y_bytes + need_csr;

    if (ws_size >= need_fused) {
        unsigned short* Y = (unsigned short*)d_ws;
        int4*  meta   = (int4*)((char*)d_ws + y_bytes);
        int*   counts = (int*)((char*)d_ws + y_bytes + meta_bytes);
        int*   rbase  = counts + 4 * N;
        int*   bsum   = rbase + 4 * N;
        int*   bpre   = bsum + 256;
        int*   rank   = bpre + 256;

        hipMemsetAsync(counts, 0, (size_t)4 * N * sizeof(int), stream);
        gemm_hist_fused<<<dim3(G_total), dim3(256), 0, stream>>>(
            Xr, Xi, W, Y, row, counts, rank, N, E, G_gemm, G_total);
        scan_block_reduce<<<dim3(NB), dim3(256), 0, stream>>>(counts, bsum, N);
        scan_bsum<<<dim3(1), dim3(256), 0, stream>>>(bsum, bpre, NB);
        scan_final<<<dim3(NB), dim3(256), 0, stream>>>(counts, bpre, rbase, N);
        fill_csr_rank<<<dim3(EB4), dim3(256), 0, stream>>>(
            row, col, Lr, Li, rbase, rank, meta, N, E);
        gather_fused<<<dim3((N + 3) / 4), dim3(256), 0, stream>>>(
            Y, Xr, Xi, rbase /* == offsets */, meta, out, N, E);
    } else if (ws_size >= need_csr) {
        int4* meta    = (int4*)d_ws;
        int*  counts  = (int*)((char*)d_ws + meta_bytes);
        int*  rbase   = counts + 4 * N;
        int*  bsum    = rbase + 4 * N;
        int*  bpre    = bsum + 256;
        int*  rank    = bpre + 256;

        hipMemsetAsync(counts, 0, (size_t)4 * N * sizeof(int), stream);
        hist_rank_fb<<<dim3(EB4), dim3(256), 0, stream>>>(row, counts, rank, N, E);
        scan_block_reduce<<<dim3(NB), dim3(256), 0, stream>>>(counts, bsum, N);
        scan_bsum<<<dim3(1), dim3(256), 0, stream>>>(bsum, bpre, NB);
        scan_final<<<dim3(NB), dim3(256), 0, stream>>>(counts, bpre, rbase, N);
        fill_csr_rank<<<dim3(EB4), dim3(256), 0, stream>>>(
            row, col, Lr, Li, rbase, rank, meta, N, E);
        gather_nodes<<<dim3((N + 3) / 4), dim3(256), 0, stream>>>(
            Xr, Xi, rbase, meta, out, N, E);
        gemm_inplace<<<dim3((N + 31) / 32), dim3(256), 0, stream>>>(out, W, Xr, N);
        gemm_inplace<<<dim3((N + 31) / 32), dim3(256), 0, stream>>>(
            out + (size_t)N * CC, W, Xi, N);
    } else {
        hipMemsetAsync(out, 0, (size_t)2 * N * CC * sizeof(float), stream);
        scatter_edges<<<dim3((E + 3) / 4), dim3(256), 0, stream>>>(
            Xr, Xi, Lr, Li, row, col, out, N, E);
        gemm_inplace<<<dim3((N + 31) / 32), dim3(256), 0, stream>>>(out, W, Xr, N);
        gemm_inplace<<<dim3((N + 31) / 32), dim3(256), 0, stream>>>(
            out + (size_t)N * CC, W, Xi, N);
    }
}